// Round 13
// baseline (354.739 us; speedup 1.0000x reference)
//
#include <hip/hip_runtime.h>

#define B_    4
#define HIMG  256
#define WIMG  256
#define C_    128
#define NH_   4
#define WS8   8
#define L_    64
#define NWX   32
#define NPATCH (HIMG*WIMG)           // 65536
#define TTOT  (NPATCH + 200)         // 65736
#define SCALE 0.17677669529663689f   // 32^-0.5

typedef __bf16 bf16x8 __attribute__((ext_vector_type(8)));
typedef __bf16 bf16x4 __attribute__((ext_vector_type(4)));
typedef float  f32x4  __attribute__((ext_vector_type(4)));

// ---- shared memory: ONE window per 256-thread block, 53248 B ----
// 3 blocks/CU: 3*53248 = 159744 <= 163840 with 4KB slack (R12's 54272 left
// only 1KB and the 3rd block never fit -> occupancy plateaued at ~22%).
// per-wave scratch @ w*13312:
//   [64][72] bf16  Q(cols 0..31)|K(cols 32..63); P overlays after frags in regs
//   V^T swizzled  @ +9216: logical (d,tok) d<32,tok<64 at byte
//                  (d*128 + tok*2) ^ ((d&7)<<4)   [4096 B, ~2-way banks]
// px exchange [64][136] bf16 overlays scratch after barrier.
#define WV_BYTES   13312
#define WIN_BYTES  (4*WV_BYTES)      // 53248
#define QK_STRIDE  72
#define KOFF       32
#define VT_OFF     9216
#define PX_STRIDE  136
#define VSWZ(d, tokbyte) (((d) * 128 + (tokbyte)) ^ (((d) & 7) << 4))

// ---- workspace layout (bytes) ----
#define WS_WQ     0          // 384*128 bf16 = 98304
#define WS_WP     98304      // 128*128 bf16 = 32768
#define WS_BIASP  131072     // 4*64*16*4 f32 = 65536  (biasP[h][row][lo][nt])
#define WS_PXTOK  196608     // 800*128 f32 = 409600

// ---------------------------------------------------------------- prep (320 blocks, ~5us)
__global__ __launch_bounds__(256)
void prep_kernel(const float* __restrict__ Wq, const float* __restrict__ Wp,
                 const float* __restrict__ rel_table, const int* __restrict__ rel_index,
                 unsigned short* __restrict__ wq_b, unsigned short* __restrict__ wp_b,
                 float* __restrict__ biasP) {
    int id = blockIdx.x * 256 + threadIdx.x;
    if (id < 49152) {
        __bf16 v = (__bf16)Wq[id];
        wq_b[id] = *(unsigned short*)&v;
    } else if (id < 65536) {
        int i = id - 49152;
        __bf16 v = (__bf16)Wp[i];
        wp_b[i] = *(unsigned short*)&v;
    } else if (id < 81920) {
        int t = id - 65536;
        int h = t >> 12, ij = t & 4095;
        int row = ij >> 6, col = ij & 63;
        biasP[((h * 64 + row) * 16 + (col & 15)) * 4 + (col >> 4)] =
            rel_table[rel_index[ij] * 4 + h];
    }
}

// ---------------------------------------------------------------- window kernel
// One window, 4 waves (wave = head). Scratch-free; targets 3 blocks/CU.
__global__ __launch_bounds__(256)
void win1_kernel(const float* __restrict__ x, const float* __restrict__ mask,
                 const unsigned short* __restrict__ wq_u, const float* __restrict__ bqkv,
                 const unsigned short* __restrict__ wp_u, const float* __restrict__ bproj,
                 const float* __restrict__ biasP, float* __restrict__ out) {
    __shared__ __align__(16) char SMEM[WIN_BYTES];
    const __bf16* wq = (const __bf16*)wq_u;
    const __bf16* wp = (const __bf16*)wp_u;
    const int tid = threadIdx.x;
    const f32x4 zz = {0.f, 0.f, 0.f, 0.f};

    const int w   = tid >> 6;            // wave == head
    const int l   = tid & 63;
    const int lo  = l & 15;
    const int hi  = l >> 4;

    const int gw = blockIdx.x;           // 0..4095
    const int b  = gw >> 10;
    const int wi = (gw >> 5) & 31;
    const int wj = gw & 31;

    __bf16* SW  = (__bf16*)(SMEM + w * WV_BYTES);   // [64][72]: Q|K, later P
    char*   VTc = SMEM + w * WV_BYTES + VT_OFF;     // swizzled V^T (byte-addressed)
    __bf16* PXU = (__bf16*)SMEM;                    // [64][136]: px union

    // ---------------- phase 1: QKV accumulators
    const float* xw = x + (((size_t)(b * HIMG) + wi * WS8) * WIMG + wj * WS8) * C_;
    const float* arow[4];
#pragma unroll
    for (int mt = 0; mt < 4; ++mt) {
        int t = mt * 16 + lo;
        arow[mt] = xw + ((size_t)(t >> 3) * WIMG + (t & 7)) * C_ + hi * 8;
    }
    int nbase[6];
    const __bf16* brow[6];
#pragma unroll
    for (int g = 0; g < 3; ++g) {
        nbase[2 * g]     = g * 128 + 32 * w;
        nbase[2 * g + 1] = g * 128 + 32 * w + 16;
    }
#pragma unroll
    for (int nt = 0; nt < 6; ++nt)
        brow[nt] = wq + (size_t)(nbase[nt] + lo) * C_ + hi * 8;

    f32x4 acc[4][6];
#pragma unroll
    for (int mt = 0; mt < 4; ++mt)
#pragma unroll
        for (int nt = 0; nt < 6; ++nt) acc[mt][nt] = zz;

#pragma unroll
    for (int ks = 0; ks < 4; ++ks) {
        bf16x8 a[4], bb[6];
#pragma unroll
        for (int mt = 0; mt < 4; ++mt) {
            const float* pa = arow[mt] + ks * 32;
            float4 v0 = *(const float4*)pa;
            float4 v1 = *(const float4*)(pa + 4);
            bf16x8 av;
            av[0] = (__bf16)v0.x; av[1] = (__bf16)v0.y; av[2] = (__bf16)v0.z; av[3] = (__bf16)v0.w;
            av[4] = (__bf16)v1.x; av[5] = (__bf16)v1.y; av[6] = (__bf16)v1.z; av[7] = (__bf16)v1.w;
            a[mt] = av;
        }
#pragma unroll
        for (int nt = 0; nt < 6; ++nt)
            bb[nt] = *(const bf16x8*)(brow[nt] + ks * 32);
#pragma unroll
        for (int mt = 0; mt < 4; ++mt)
#pragma unroll
            for (int nt = 0; nt < 6; ++nt)
                acc[mt][nt] = __builtin_amdgcn_mfma_f32_16x16x32_bf16(a[mt], bb[nt], acc[mt][nt], 0, 0, 0);
    }

    // ---------------- scatter Q, K, V^T to LDS (write all, then read)
#pragma unroll
    for (int nt = 0; nt < 6; ++nt) {
        float bq = bqkv[nbase[nt] + lo];
        if (nt < 2) {
            int col = nt * 16 + lo;
#pragma unroll
            for (int mt = 0; mt < 4; ++mt)
#pragma unroll
                for (int r = 0; r < 4; ++r)
                    SW[(mt * 16 + hi * 4 + r) * QK_STRIDE + col] = (__bf16)(acc[mt][nt][r] + bq);
        } else if (nt < 4) {
            int col = KOFF + (nt - 2) * 16 + lo;
#pragma unroll
            for (int mt = 0; mt < 4; ++mt)
#pragma unroll
                for (int r = 0; r < 4; ++r)
                    SW[(mt * 16 + hi * 4 + r) * QK_STRIDE + col] = (__bf16)(acc[mt][nt][r] + bq);
        } else {
            int d = (nt - 4) * 16 + lo;
#pragma unroll
            for (int mt = 0; mt < 4; ++mt) {
                bf16x4 vv;
#pragma unroll
                for (int r = 0; r < 4; ++r) vv[r] = (__bf16)(acc[mt][nt][r] + bq);
                *(bf16x4*)(VTc + VSWZ(d, mt * 32 + hi * 8)) = vv;
            }
        }
    }

    bf16x8 aq[4], bk[4];
#pragma unroll
    for (int mt = 0; mt < 4; ++mt)
        aq[mt] = *(const bf16x8*)&SW[(mt * 16 + lo) * QK_STRIDE + hi * 8];
#pragma unroll
    for (int nt = 0; nt < 4; ++nt)
        bk[nt] = *(const bf16x8*)&SW[(nt * 16 + lo) * QK_STRIDE + KOFF + hi * 8];

    // hoist proj weights (L2-hot) before the barrier: post-barrier proj phase
    // becomes pure LDS+MFMA (no L2 round trip on the critical path)
    bf16x8 bwreg[4][2];
#pragma unroll
    for (int nt = 0; nt < 2; ++nt) {
        const __bf16* wpr = wp + (size_t)(32 * w + nt * 16 + lo) * C_ + hi * 8;
#pragma unroll
        for (int ks = 0; ks < 4; ++ks)
            bwreg[ks][nt] = *(const bf16x8*)(wpr + ks * 32);
    }
    float bp0 = bproj[32 * w + lo];
    float bp1 = bproj[32 * w + 16 + lo];

    // ---------------- QK^T
    f32x4 lg[4][4];
#pragma unroll
    for (int mt = 0; mt < 4; ++mt)
#pragma unroll
        for (int nt = 0; nt < 4; ++nt)
            lg[mt][nt] = __builtin_amdgcn_mfma_f32_16x16x32_bf16(aq[mt], bk[nt], zz, 0, 0, 0);

    // ---------------- softmax, P -> scratch (overlays Q/K; both in regs)
    const float* maskW = mask + (size_t)(wi * NWX + wj) * 4096;
#pragma unroll
    for (int mt = 0; mt < 4; ++mt) {
#pragma unroll
        for (int r = 0; r < 4; ++r) {
            int row = mt * 16 + hi * 4 + r;
            f32x4 bv4 = *(const f32x4*)&biasP[((w * 64 + row) * 16 + lo) * 4];
            const float* mrow = maskW + row * 64 + lo;
            float v[4];
            float m = -1e30f;
#pragma unroll
            for (int nt = 0; nt < 4; ++nt) {
                float t = lg[mt][nt][r] * SCALE + bv4[nt] + mrow[nt * 16];
                v[nt] = t;
                m = fmaxf(m, t);
            }
            m = fmaxf(m, __shfl_xor(m, 1));
            m = fmaxf(m, __shfl_xor(m, 2));
            m = fmaxf(m, __shfl_xor(m, 4));
            m = fmaxf(m, __shfl_xor(m, 8));
            float s = 0.f;
#pragma unroll
            for (int nt = 0; nt < 4; ++nt) { v[nt] = __expf(v[nt] - m); s += v[nt]; }
            s += __shfl_xor(s, 1);
            s += __shfl_xor(s, 2);
            s += __shfl_xor(s, 4);
            s += __shfl_xor(s, 8);
            float inv = 1.0f / s;
#pragma unroll
            for (int nt = 0; nt < 4; ++nt)
                SW[row * QK_STRIDE + nt * 16 + lo] = (__bf16)(v[nt] * inv);
        }
    }

    // ---------------- PV (V^T via swizzled reads)
    f32x4 pv[4][2];
#pragma unroll
    for (int mt = 0; mt < 4; ++mt)
#pragma unroll
        for (int nt = 0; nt < 2; ++nt) pv[mt][nt] = zz;
#pragma unroll
    for (int ks = 0; ks < 2; ++ks) {
        bf16x8 ap[4], bv[2];
#pragma unroll
        for (int mt = 0; mt < 4; ++mt)
            ap[mt] = *(const bf16x8*)&SW[(mt * 16 + lo) * QK_STRIDE + ks * 32 + hi * 8];
#pragma unroll
        for (int nt = 0; nt < 2; ++nt) {
            int d = nt * 16 + lo;
            int byte0 = VSWZ(d, ks * 64 + hi * 16);   // tokbyte bit3 clear -> +8 safe
            bf16x4 b0 = *(const bf16x4*)(VTc + byte0);
            bf16x4 b1 = *(const bf16x4*)(VTc + byte0 + 8);
            bf16x8 bb;
#pragma unroll
            for (int u = 0; u < 4; ++u) { bb[u] = b0[u]; bb[u + 4] = b1[u]; }
            bv[nt] = bb;
        }
#pragma unroll
        for (int mt = 0; mt < 4; ++mt)
#pragma unroll
            for (int nt = 0; nt < 2; ++nt)
                pv[mt][nt] = __builtin_amdgcn_mfma_f32_16x16x32_bf16(ap[mt], bv[nt], pv[mt][nt], 0, 0, 0);
    }

    // ---------------- px exchange through scratch union
    __syncthreads();   // all waves done reading their scratch
#pragma unroll
    for (int mt = 0; mt < 4; ++mt)
#pragma unroll
        for (int nt = 0; nt < 2; ++nt)
#pragma unroll
            for (int r = 0; r < 4; ++r)
                PXU[(mt * 16 + hi * 4 + r) * PX_STRIDE + 32 * w + nt * 16 + lo] = (__bf16)pv[mt][nt][r];
    __syncthreads();

    // ---------------- proj (wave w -> out cols [32w, 32w+32)); weights pre-loaded
    f32x4 po[4][2];
#pragma unroll
    for (int mt = 0; mt < 4; ++mt)
#pragma unroll
        for (int nt = 0; nt < 2; ++nt) po[mt][nt] = zz;
#pragma unroll
    for (int ks = 0; ks < 4; ++ks) {
        bf16x8 apx[4];
#pragma unroll
        for (int mt = 0; mt < 4; ++mt)
            apx[mt] = *(const bf16x8*)&PXU[(mt * 16 + lo) * PX_STRIDE + ks * 32 + hi * 8];
#pragma unroll
        for (int mt = 0; mt < 4; ++mt)
#pragma unroll
            for (int nt = 0; nt < 2; ++nt)
                po[mt][nt] = __builtin_amdgcn_mfma_f32_16x16x32_bf16(apx[mt], bwreg[ks][nt], po[mt][nt], 0, 0, 0);
    }
    float* outb = out + (size_t)b * TTOT * C_;
#pragma unroll
    for (int mt = 0; mt < 4; ++mt) {
#pragma unroll
        for (int r = 0; r < 4; ++r) {
            int row = mt * 16 + hi * 4 + r;
            int tok = (wi * 8 + (row >> 3)) * WIMG + wj * 8 + (row & 7);
            float* orow = outb + (size_t)tok * C_ + 32 * w + lo;
            orow[0]  = po[mt][0][r] + bp0;
            orow[16] = po[mt][1][r] + bp1;
        }
    }
}

// ---------------------------------------------------------------- token attention
// One block per (bs,h): computes its own head-slice qkv from raw f32 weights
// (removes tok_qkv launch + qkvT workspace round trip), then attention.
__global__ __launch_bounds__(256)
void tok_attn2_kernel(const float* __restrict__ det, const float* __restrict__ inter,
                      const float* __restrict__ Wq, const float* __restrict__ bq,
                      float* __restrict__ px_tok) {
    __shared__ __align__(16) char TSM[47600];
    __bf16* xs  = (__bf16*)TSM;              // [100][136]
    __bf16* qs  = (__bf16*)(TSM + 27200);    // [100][34]
    __bf16* ks2 = (__bf16*)(TSM + 34000);
    __bf16* vs2 = (__bf16*)(TSM + 40800);

    const int bid = blockIdx.x;      // bs*4 + h
    const int h   = bid & 3;
    const int bs  = bid >> 2;        // 0..7 = b*2+set
    const int b   = bs >> 1;
    const int set = bs & 1;
    const int tid = threadIdx.x;
    const float* src = set ? (inter + (size_t)b * 100 * C_) : (det + (size_t)b * 100 * C_);

    for (int i = tid; i < 12800; i += 256) {
        int t = i >> 7, c = i & 127;
        xs[t * PX_STRIDE + c] = (__bf16)src[i];
    }
    __syncthreads();

    // head-slice qkv: mat in {q,k,v}, d in [0,32), t in [0,100)
    for (int idx = tid; idx < 9600; idx += 256) {
        int md = idx / 100;              // mat*32 + d
        int t  = idx - md * 100;
        int mat = md >> 5, d = md & 31;
        int n = mat * 128 + 32 * h + d;
        const float* wr = Wq + (size_t)n * C_;
        float s = 0.f;
#pragma unroll
        for (int k = 0; k < 128; k += 8) {
            bf16x8 xv = *(const bf16x8*)&xs[t * PX_STRIDE + k];
            float4 w0 = *(const float4*)(wr + k);
            float4 w1 = *(const float4*)(wr + k + 4);
            s += (float)xv[0] * w0.x + (float)xv[1] * w0.y + (float)xv[2] * w0.z + (float)xv[3] * w0.w
               + (float)xv[4] * w1.x + (float)xv[5] * w1.y + (float)xv[6] * w1.z + (float)xv[7] * w1.w;
        }
        s += bq[n];
        __bf16* dst = (mat == 0) ? qs : (mat == 1) ? ks2 : vs2;
        dst[t * 34 + d] = (__bf16)s;
    }
    __syncthreads();

    if (tid < 100) {
        int t = tid;
        float qreg[32];
#pragma unroll
        for (int d = 0; d < 32; ++d) qreg[d] = (float)qs[t * 34 + d];
        float m = -1e30f;
        for (int j = 0; j < 100; ++j) {
            float s = 0.f;
#pragma unroll
            for (int d = 0; d < 32; ++d) s += qreg[d] * (float)ks2[j * 34 + d];
            m = fmaxf(m, s * SCALE);
        }
        float sum = 0.f;
        float acc32[32];
#pragma unroll
        for (int d = 0; d < 32; ++d) acc32[d] = 0.f;
        for (int j = 0; j < 100; ++j) {
            float s = 0.f;
#pragma unroll
            for (int d = 0; d < 32; ++d) s += qreg[d] * (float)ks2[j * 34 + d];
            float p = __expf(s * SCALE - m);
            sum += p;
#pragma unroll
            for (int d = 0; d < 32; ++d) acc32[d] += p * (float)vs2[j * 34 + d];
        }
        float inv = 1.0f / sum;
#pragma unroll
        for (int d = 0; d < 32; ++d)
            px_tok[(size_t)(bs * 100 + t) * 128 + 32 * h + d] = acc32[d] * inv;
    }
}

__global__ __launch_bounds__(256)
void tok_proj_kernel(const float* __restrict__ px_tok, const float* __restrict__ Wp,
                     const float* __restrict__ bp, float* __restrict__ out) {
    int gid = blockIdx.x * 256 + threadIdx.x;   // 0..102399
    int row = gid >> 7, c = gid & 127;
    int b = row / 200, rem = row % 200;
    const float* pr = px_tok + (size_t)row * 128;
    const float* wr = Wp + (size_t)c * 128;
    float s = 0.f;
#pragma unroll 8
    for (int k = 0; k < 128; ++k) s += pr[k] * wr[k];
    out[((size_t)b * TTOT + NPATCH + rem) * 128 + c] = s + bp[c];
}

// ---------------------------------------------------------------- launch
extern "C" void kernel_launch(void* const* d_in, const int* in_sizes, int n_in,
                              void* d_out, int out_size, void* d_ws, size_t ws_size,
                              hipStream_t stream) {
    const float* x         = (const float*)d_in[0];
    const float* det       = (const float*)d_in[1];
    const float* inter     = (const float*)d_in[2];
    const float* mask      = (const float*)d_in[3];
    const float* Wq        = (const float*)d_in[4];
    const float* bq        = (const float*)d_in[5];
    const float* Wp        = (const float*)d_in[6];
    const float* bp        = (const float*)d_in[7];
    const float* rel_table = (const float*)d_in[8];
    const int*   rel_index = (const int*)d_in[9];
    float* out = (float*)d_out;

    char* ws = (char*)d_ws;
    unsigned short* wq_b = (unsigned short*)(ws + WS_WQ);
    unsigned short* wp_b = (unsigned short*)(ws + WS_WP);
    float* biasP         = (float*)(ws + WS_BIASP);
    float* px_tok        = (float*)(ws + WS_PXTOK);

    prep_kernel<<<320, 256, 0, stream>>>(Wq, Wp, rel_table, rel_index, wq_b, wp_b, biasP);
    tok_attn2_kernel<<<32, 256, 0, stream>>>(det, inter, Wq, bq, px_tok);
    tok_proj_kernel<<<400, 256, 0, stream>>>(px_tok, Wp, bp, out);
    win1_kernel<<<4096, 256, 0, stream>>>(x, mask, wq_b, bq, wp_b, bp, biasP, out);
}